// Round 1
// baseline (4354.203 us; speedup 1.0000x reference)
//
#include <hip/hip_runtime.h>
#include <math.h>

constexpr int B_ = 64, S_ = 256, D_ = 512, H_ = 256, NC_ = 3;
constexpr int BS = B_ * S_;     // 16384
constexpr int G4 = 4 * H_;      // 1024

template<int ACT>
static __device__ __forceinline__ float activate(float v) {
  if constexpr (ACT == 1) return v > 0.f ? v : 0.f;
  else if constexpr (ACT == 2) return 1.f / (1.f + expf(-v));
  else return v;
}

// C[M,N] = act( A[M,K] @ B' + bias[N] + (ADDC ? Cin : 0) )
// BT: B is (N,K) row-major with row stride ldb (C = A B^T)
// !BT: B is (K,N) row-major with row stride ldb (C = A B)
// GATHER: A row m is embed + gidx[m]*K  (A = embed base)
template<int ACT, bool BT, bool ADDC, bool GATHER>
__global__ __launch_bounds__(256) void gemm_k(
    const float* __restrict__ A, const float* __restrict__ Bm,
    const float* __restrict__ bias, const float* __restrict__ Cin,
    float* __restrict__ C, int M, int N, int K, int ldb,
    long sA, long sB, long sC, const int* __restrict__ gidx)
{
  constexpr int BM = 128, BN = 64, BK = 16, TM = 8, TN = 4;
  __shared__ float As[BK][BM];
  __shared__ float Bs[BK][BN];
  const int z = blockIdx.z;
  const float* Ab = A + (size_t)z * sA;
  const float* Bb = Bm + (size_t)z * sB;
  float* Cb = C + (size_t)z * sC;
  const float* Qb = ADDC ? (Cin + (size_t)z * sC) : nullptr;
  const int m0 = blockIdx.x * BM, n0 = blockIdx.y * BN;
  const int tid = threadIdx.x;
  const int tx = tid & 15, ty = tid >> 4;

  float acc[TM][TN];
  #pragma unroll
  for (int i = 0; i < TM; ++i)
    #pragma unroll
    for (int j = 0; j < TN; ++j) acc[i][j] = 0.f;

  const int lr = tid >> 2;
  const int ka = (tid & 3) * 4;

  for (int kt = 0; kt < K; kt += BK) {
    #pragma unroll
    for (int h = 0; h < 2; ++h) {
      int m = m0 + lr + h * 64;
      float4 v = make_float4(0.f, 0.f, 0.f, 0.f);
      if (m < M) {
        const float* ar;
        if constexpr (GATHER) ar = A + (size_t)gidx[m] * K;
        else                  ar = Ab + (size_t)m * K;
        v = *(const float4*)(ar + kt + ka);
      }
      As[ka + 0][lr + h * 64] = v.x;
      As[ka + 1][lr + h * 64] = v.y;
      As[ka + 2][lr + h * 64] = v.z;
      As[ka + 3][lr + h * 64] = v.w;
    }
    if constexpr (BT) {
      int n = tid >> 2;
      float4 v = *(const float4*)(Bb + (size_t)(n0 + n) * ldb + kt + ka);
      Bs[ka + 0][n] = v.x; Bs[ka + 1][n] = v.y;
      Bs[ka + 2][n] = v.z; Bs[ka + 3][n] = v.w;
    } else {
      int kk = tid >> 4, nc = (tid & 15) * 4;
      float4 v = *(const float4*)(Bb + (size_t)(kt + kk) * ldb + n0 + nc);
      *(float4*)&Bs[kk][nc] = v;
    }
    __syncthreads();
    #pragma unroll
    for (int k = 0; k < BK; ++k) {
      float4 a0 = *(float4*)&As[k][ty * TM];
      float4 a1 = *(float4*)&As[k][ty * TM + 4];
      float4 b0 = *(float4*)&Bs[k][tx * TN];
      float av[TM] = {a0.x, a0.y, a0.z, a0.w, a1.x, a1.y, a1.z, a1.w};
      float bv[TN] = {b0.x, b0.y, b0.z, b0.w};
      #pragma unroll
      for (int i = 0; i < TM; ++i)
        #pragma unroll
        for (int j = 0; j < TN; ++j)
          acc[i][j] = fmaf(av[i], bv[j], acc[i][j]);
    }
    __syncthreads();
  }

  #pragma unroll
  for (int i = 0; i < TM; ++i) {
    int m = m0 + ty * TM + i;
    if (m < M) {
      #pragma unroll
      for (int j = 0; j < TN; ++j) {
        int n = n0 + tx * TN + j;
        float v = acc[i][j];
        if (bias) v += bias[n];
        if constexpr (ADDC) v += Qb[(size_t)m * (size_t)N + n];
        Cb[(size_t)m * (size_t)N + n] = activate<ACT>(v);
      }
    }
  }
}

// WhhT[dir][k][r] = Whh_dir[r][k]   (k<256 hidden, r<1024 gate-row)
__global__ __launch_bounds__(256) void whh_transpose(
    const float* __restrict__ Wf, const float* __restrict__ Wb, float* __restrict__ WhhT)
{
  int n = blockIdx.x * 256 + threadIdx.x;
  if (n >= 2 * H_ * G4) return;
  int dir = n >> 18;
  int e = n & (H_ * G4 - 1);
  int k = e >> 10;
  int r = e & (G4 - 1);
  const float* W = dir ? Wb : Wf;
  WhhT[n] = W[r * H_ + k];
}

// 64 blocks: dir = bid>>5, 2 batch elements per block. 256 threads.
__global__ __launch_bounds__(256) void lstm_rec(
    const float* __restrict__ GX, const float* __restrict__ WhhT,
    const int* __restrict__ lens, float* __restrict__ out)
{
  const int bid = blockIdx.x;
  const int dir = bid >> 5;
  const int pr = bid & 31;
  const int b0 = pr * 2, b1 = b0 + 1;
  const int tid = threadIdx.x;
  const float* W = WhhT + (size_t)dir * (H_ * G4);
  const float* gx = GX + (size_t)dir * ((size_t)BS * G4);
  const int len0 = lens[b0], len1 = lens[b1];
  __shared__ float hs0[H_], hs1[H_];
  __shared__ float act0[G4], act1[G4];
  hs0[tid] = 0.f; hs1[tid] = 0.f;
  float c0 = 0.f, c1 = 0.f;
  const int col = tid * 4;
  const int gt = tid >> 6;   // 0:i 1:f 2:g 3:o
  __syncthreads();

  for (int t = 0; t < S_; ++t) {
    const int pos0 = dir ? (t < len0 ? len0 - 1 - t : t) : t;
    const int pos1 = dir ? (t < len1 ? len1 - 1 - t : t) : t;
    float4 s0 = *(const float4*)(gx + ((size_t)(b0 * S_ + pos0)) * G4 + col);
    float4 s1 = *(const float4*)(gx + ((size_t)(b1 * S_ + pos1)) * G4 + col);
    const float* wp = W + col;
    #pragma unroll 8
    for (int k = 0; k < H_; ++k) {
      float4 wv = *(const float4*)wp; wp += G4;
      float h0 = hs0[k], h1 = hs1[k];
      s0.x = fmaf(h0, wv.x, s0.x); s0.y = fmaf(h0, wv.y, s0.y);
      s0.z = fmaf(h0, wv.z, s0.z); s0.w = fmaf(h0, wv.w, s0.w);
      s1.x = fmaf(h1, wv.x, s1.x); s1.y = fmaf(h1, wv.y, s1.y);
      s1.z = fmaf(h1, wv.z, s1.z); s1.w = fmaf(h1, wv.w, s1.w);
    }
    float4 a0, a1;
    if (gt == 2) {
      a0.x = tanhf(s0.x); a0.y = tanhf(s0.y); a0.z = tanhf(s0.z); a0.w = tanhf(s0.w);
      a1.x = tanhf(s1.x); a1.y = tanhf(s1.y); a1.z = tanhf(s1.z); a1.w = tanhf(s1.w);
    } else {
      a0.x = 1.f / (1.f + expf(-s0.x)); a0.y = 1.f / (1.f + expf(-s0.y));
      a0.z = 1.f / (1.f + expf(-s0.z)); a0.w = 1.f / (1.f + expf(-s0.w));
      a1.x = 1.f / (1.f + expf(-s1.x)); a1.y = 1.f / (1.f + expf(-s1.y));
      a1.z = 1.f / (1.f + expf(-s1.z)); a1.w = 1.f / (1.f + expf(-s1.w));
    }
    *(float4*)&act0[col] = a0;
    *(float4*)&act1[col] = a1;
    __syncthreads();
    {
      float iv = act0[tid], fv = act0[H_ + tid], gv = act0[2 * H_ + tid], ov = act0[3 * H_ + tid];
      float cn = fmaf(fv, c0, iv * gv);
      float hn = ov * tanhf(cn);
      bool v = t < len0;
      if (v) { c0 = cn; hs0[tid] = hn; }
      out[((size_t)(b0 * S_ + pos0)) * (2 * H_) + dir * H_ + tid] = v ? hn : 0.f;
    }
    {
      float iv = act1[tid], fv = act1[H_ + tid], gv = act1[2 * H_ + tid], ov = act1[3 * H_ + tid];
      float cn = fmaf(fv, c1, iv * gv);
      float hn = ov * tanhf(cn);
      bool v = t < len1;
      if (v) { c1 = cn; hs1[tid] = hn; }
      out[((size_t)(b1 * S_ + pos1)) * (2 * H_) + dir * H_ + tid] = v ? hn : 0.f;
    }
    __syncthreads();
  }
}

__global__ __launch_bounds__(512) void asps_k(
    const float* __restrict__ lstm, const float* __restrict__ amask,
    const int* __restrict__ alen, float* __restrict__ asps)
{
  int b = blockIdx.x, d = threadIdx.x;
  float acc = 0.f;
  for (int t = 0; t < S_; ++t)
    if (amask[b * S_ + t] == 0.f) acc += lstm[((size_t)(b * S_ + t)) * D_ + d];
  asps[b * D_ + d] = acc / (float)alen[b];
}

// softmax over rows of score (B*S rows of length S), adding asps_mask[b,:]
__global__ __launch_bounds__(256) void softmax_rows(
    float* __restrict__ p_, const float* __restrict__ mask)
{
  const int row = blockIdx.x;
  const int b = row >> 8;
  const int tid = threadIdx.x;
  float* p = p_ + (size_t)row * S_;
  float v = p[tid] + mask[(b << 8) | tid];
  float m = v;
  #pragma unroll
  for (int off = 32; off > 0; off >>= 1) m = fmaxf(m, __shfl_xor(m, off));
  __shared__ float r1[4];
  __shared__ float r2[4];
  const int w = tid >> 6, l = tid & 63;
  if (l == 0) r1[w] = m;
  __syncthreads();
  m = fmaxf(fmaxf(r1[0], r1[1]), fmaxf(r1[2], r1[3]));
  float e = expf(v - m);
  float s = e;
  #pragma unroll
  for (int off = 32; off > 0; off >>= 1) s += __shfl_xor(s, off);
  if (l == 0) r2[w] = s;
  __syncthreads();
  s = r2[0] + r2[1] + r2[2] + r2[3];
  p[tid] = e / s;
}

// x_out = scale*lin + (1-scale)*x_in
__global__ __launch_bounds__(256) void xupdate(
    const float4* __restrict__ xin, const float4* __restrict__ sc,
    const float4* __restrict__ lin, float4* __restrict__ xout, int n4)
{
  int i = blockIdx.x * 256 + threadIdx.x;
  if (i < n4) {
    float4 s = sc[i], l = lin[i], xv = xin[i], o;
    o.x = s.x * l.x + (1.f - s.x) * xv.x;
    o.y = s.y * l.y + (1.f - s.y) * xv.y;
    o.z = s.z * l.z + (1.f - s.z) * xv.z;
    o.w = s.w * l.w + (1.f - s.w) * xv.w;
    xout[i] = o;
  }
}

// sc[b,k] = softmax_k( dot(Qp[b], Kp[b,k]) / sqrt(512) + sent_mask[b,k] )
__global__ __launch_bounds__(256) void final_sc_k(
    const float* __restrict__ Qp, const float* __restrict__ Kp,
    const float* __restrict__ smask, float* __restrict__ outsc)
{
  int b = blockIdx.x, tid = threadIdx.x;
  __shared__ float q[D_];
  q[tid] = Qp[b * D_ + tid];
  q[tid + 256] = Qp[b * D_ + tid + 256];
  __syncthreads();
  const float4* kr = (const float4*)(Kp + ((size_t)(b * S_ + tid)) * D_);
  float acc = 0.f;
  #pragma unroll 4
  for (int d = 0; d < D_ / 4; ++d) {
    float4 kv = kr[d];
    acc += q[4 * d] * kv.x + q[4 * d + 1] * kv.y + q[4 * d + 2] * kv.z + q[4 * d + 3] * kv.w;
  }
  float v = acc / sqrtf((float)D_) + smask[b * S_ + tid];
  float m = v;
  #pragma unroll
  for (int off = 32; off > 0; off >>= 1) m = fmaxf(m, __shfl_xor(m, off));
  __shared__ float r1[4];
  __shared__ float r2[4];
  const int w = tid >> 6, l = tid & 63;
  if (l == 0) r1[w] = m;
  __syncthreads();
  m = fmaxf(fmaxf(r1[0], r1[1]), fmaxf(r1[2], r1[3]));
  float e = expf(v - m);
  float s = e;
  #pragma unroll
  for (int off = 32; off > 0; off >>= 1) s += __shfl_xor(s, off);
  if (l == 0) r2[w] = s;
  __syncthreads();
  s = r2[0] + r2[1] + r2[2] + r2[3];
  outsc[b * S_ + tid] = e / s;
}

__global__ __launch_bounds__(512) void out_vec_k(
    const float* __restrict__ sc, const float* __restrict__ Vp, float* __restrict__ outv)
{
  int b = blockIdx.x, d = threadIdx.x;
  __shared__ float s[S_];
  if (d < S_) s[d] = sc[b * S_ + d];
  __syncthreads();
  float acc = 0.f;
  for (int k = 0; k < S_; ++k) acc = fmaf(s[k], Vp[((size_t)(b * S_ + k)) * D_ + d], acc);
  outv[b * D_ + d] = acc;
}

__global__ __launch_bounds__(192) void logits_k(
    const float* __restrict__ outv, const float* __restrict__ Wd,
    const float* __restrict__ bd, float* __restrict__ out)
{
  int b = blockIdx.x;
  int c = threadIdx.x >> 6, l = threadIdx.x & 63;
  float acc = 0.f;
  for (int d = l; d < D_; d += 64) acc = fmaf(outv[b * D_ + d], Wd[c * D_ + d], acc);
  #pragma unroll
  for (int off = 32; off > 0; off >>= 1) acc += __shfl_down(acc, off);
  if (l == 0) out[b * NC_ + c] = acc + bd[c];
}

extern "C" void kernel_launch(void* const* d_in, const int* in_sizes, int n_in,
                              void* d_out, int out_size, void* d_ws, size_t ws_size,
                              hipStream_t stream)
{
  const int*   seqs_id   = (const int*)d_in[0];
  const int*   seqs_len  = (const int*)d_in[1];
  const int*   asps_len  = (const int*)d_in[2];
  const float* asps_mask = (const float*)d_in[3];
  const float* sent_mask = (const float*)d_in[4];
  const float* embed     = (const float*)d_in[5];
  const float* Wih_f     = (const float*)d_in[6];
  const float* Whh_f     = (const float*)d_in[7];
  const float* b_f       = (const float*)d_in[8];
  const float* Wih_b     = (const float*)d_in[9];
  const float* Whh_b     = (const float*)d_in[10];
  const float* b_b       = (const float*)d_in[11];
  const float* W_cpt     = (const float*)d_in[12];
  const float* b_cpt     = (const float*)d_in[13];
  const float* W_as      = (const float*)d_in[14];
  const float* b_as      = (const float*)d_in[15];
  const float* Wq        = (const float*)d_in[16];
  const float* bq        = (const float*)d_in[17];
  const float* Wk        = (const float*)d_in[18];
  const float* bk        = (const float*)d_in[19];
  const float* Wv        = (const float*)d_in[20];
  const float* bv        = (const float*)d_in[21];
  const float* Wd        = (const float*)d_in[22];
  const float* bd        = (const float*)d_in[23];

  float* w = (float*)d_ws;
  const size_t off_whht  = 0;
  const size_t off_gx    = off_whht + 2ul * H_ * G4;            // 524288
  const size_t off_lstm  = off_gx + 2ul * BS * G4;              // GX: 33.55M floats
  const size_t off_x     = off_lstm + (size_t)BS * D_;
  const size_t off_score = off_x + (size_t)BS * D_;
  const size_t off_asps  = off_score + (size_t)B_ * S_ * S_;
  const size_t off_qp    = off_asps + (size_t)B_ * D_;
  const size_t off_outv  = off_qp + (size_t)B_ * D_;
  // overlays on GX region (GX dead after lstm_rec):
  const size_t off_attn  = off_gx;
  const size_t off_lin   = off_gx + (size_t)BS * D_;
  const size_t off_scale = off_gx + 2ul * BS * D_;

  float* WhhT  = w + off_whht;
  float* GX    = w + off_gx;
  float* lstm  = w + off_lstm;
  float* xbuf  = w + off_x;
  float* score = w + off_score;
  float* aspsb = w + off_asps;
  float* qp    = w + off_qp;
  float* outv  = w + off_outv;
  float* attn  = w + off_attn;
  float* lin   = w + off_lin;
  float* scl   = w + off_scale;
  float* logits = (float*)d_out;
  float* outsc  = (float*)d_out + B_ * NC_;

  whh_transpose<<<2048, 256, 0, stream>>>(Whh_f, Whh_b, WhhT);

  // input GEMMs with fused embedding gather; bias folded in
  gemm_k<0, true, false, true><<<dim3(BS / 128, G4 / 64, 1), 256, 0, stream>>>(
      embed, Wih_f, b_f, nullptr, GX, BS, G4, D_, D_, 0, 0, 0, seqs_id);
  gemm_k<0, true, false, true><<<dim3(BS / 128, G4 / 64, 1), 256, 0, stream>>>(
      embed, Wih_b, b_b, nullptr, GX + (size_t)BS * G4, BS, G4, D_, D_, 0, 0, 0, seqs_id);

  lstm_rec<<<64, 256, 0, stream>>>(GX, WhhT, seqs_len, lstm);
  asps_k<<<B_, D_, 0, stream>>>(lstm, asps_mask, asps_len, aspsb);

  for (int it = 0; it < 2; ++it) {
    const float* xin = (it == 0) ? lstm : xbuf;
    gemm_k<0, true, false, false><<<dim3(2, 4, B_), 256, 0, stream>>>(
        xin, lstm, nullptr, nullptr, score, S_, S_, D_, D_,
        (long)S_ * D_, (long)S_ * D_, (long)S_ * S_, nullptr);
    softmax_rows<<<BS, 256, 0, stream>>>(score, asps_mask);
    gemm_k<0, false, false, false><<<dim3(2, 8, B_), 256, 0, stream>>>(
        score, lstm, nullptr, nullptr, attn, S_, D_, S_, D_,
        (long)S_ * S_, (long)S_ * D_, (long)S_ * D_, nullptr);
    // linear_out = relu(attn @ Wc[:, :512]^T + x @ Wc[:, 512:]^T + b_cpt)
    gemm_k<0, true, false, false><<<dim3(BS / 128, D_ / 64, 1), 256, 0, stream>>>(
        attn, W_cpt, b_cpt, nullptr, lin, BS, D_, D_, 2 * D_, 0, 0, 0, nullptr);
    gemm_k<1, true, true, false><<<dim3(BS / 128, D_ / 64, 1), 256, 0, stream>>>(
        xin, W_cpt + D_, nullptr, lin, lin, BS, D_, D_, 2 * D_, 0, 0, 0, nullptr);
    gemm_k<2, true, false, false><<<dim3(BS / 128, D_ / 64, 1), 256, 0, stream>>>(
        xin, W_as, b_as, nullptr, scl, BS, D_, D_, D_, 0, 0, 0, nullptr);
    xupdate<<<(BS * D_ / 4 + 255) / 256, 256, 0, stream>>>(
        (const float4*)xin, (const float4*)scl, (const float4*)lin, (float4*)xbuf, BS * D_ / 4);
  }

  float* Kp = attn;   // reuse (attn/lin dead after CPT)
  float* Vp = lin;
  gemm_k<0, true, false, false><<<dim3(BS / 128, D_ / 64, 1), 256, 0, stream>>>(
      xbuf, Wk, bk, nullptr, Kp, BS, D_, D_, D_, 0, 0, 0, nullptr);
  gemm_k<0, true, false, false><<<dim3(BS / 128, D_ / 64, 1), 256, 0, stream>>>(
      xbuf, Wv, bv, nullptr, Vp, BS, D_, D_, D_, 0, 0, 0, nullptr);
  gemm_k<0, true, false, false><<<dim3(1, D_ / 64, 1), 256, 0, stream>>>(
      aspsb, Wq, bq, nullptr, qp, B_, D_, D_, D_, 0, 0, 0, nullptr);

  final_sc_k<<<B_, 256, 0, stream>>>(qp, Kp, sent_mask, outsc);
  out_vec_k<<<B_, D_, 0, stream>>>(outsc, Vp, outv);
  logits_k<<<B_, 192, 0, stream>>>(outv, Wd, bd, logits);
}

// Round 2
// 4005.961 us; speedup vs baseline: 1.0869x; 1.0869x over previous
//
#include <hip/hip_runtime.h>
#include <math.h>

constexpr int B_ = 64, S_ = 256, D_ = 512, H_ = 256, NC_ = 3;
constexpr int BS = B_ * S_;     // 16384
constexpr int G4 = 4 * H_;      // 1024

template<int ACT>
static __device__ __forceinline__ float activate(float v) {
  if constexpr (ACT == 1) return v > 0.f ? v : 0.f;
  else if constexpr (ACT == 2) return 1.f / (1.f + expf(-v));
  else return v;
}

// C[M,N] = act( A[M,K] @ B' + bias[N] + (ADDC ? Cin : 0) )
// BT: B is (N,K) row-major with row stride ldb (C = A B^T)
// !BT: B is (K,N) row-major with row stride ldb (C = A B)
// GATHER: A row m is embed + gidx[m]*K  (A = embed base)
template<int ACT, bool BT, bool ADDC, bool GATHER>
__global__ __launch_bounds__(256) void gemm_k(
    const float* __restrict__ A, const float* __restrict__ Bm,
    const float* __restrict__ bias, const float* __restrict__ Cin,
    float* __restrict__ C, int M, int N, int K, int ldb,
    long sA, long sB, long sC, const int* __restrict__ gidx)
{
  constexpr int BM = 128, BN = 64, BK = 16, TM = 8, TN = 4;
  __shared__ float As[BK][BM];
  __shared__ float Bs[BK][BN];
  const int z = blockIdx.z;
  const float* Ab = A + (size_t)z * sA;
  const float* Bb = Bm + (size_t)z * sB;
  float* Cb = C + (size_t)z * sC;
  const float* Qb = ADDC ? (Cin + (size_t)z * sC) : nullptr;
  const int m0 = blockIdx.x * BM, n0 = blockIdx.y * BN;
  const int tid = threadIdx.x;
  const int tx = tid & 15, ty = tid >> 4;

  float acc[TM][TN];
  #pragma unroll
  for (int i = 0; i < TM; ++i)
    #pragma unroll
    for (int j = 0; j < TN; ++j) acc[i][j] = 0.f;

  const int lr = tid >> 2;
  const int ka = (tid & 3) * 4;

  for (int kt = 0; kt < K; kt += BK) {
    #pragma unroll
    for (int h = 0; h < 2; ++h) {
      int m = m0 + lr + h * 64;
      float4 v = make_float4(0.f, 0.f, 0.f, 0.f);
      if (m < M) {
        const float* ar;
        if constexpr (GATHER) ar = A + (size_t)gidx[m] * K;
        else                  ar = Ab + (size_t)m * K;
        v = *(const float4*)(ar + kt + ka);
      }
      As[ka + 0][lr + h * 64] = v.x;
      As[ka + 1][lr + h * 64] = v.y;
      As[ka + 2][lr + h * 64] = v.z;
      As[ka + 3][lr + h * 64] = v.w;
    }
    if constexpr (BT) {
      int n = tid >> 2;
      float4 v = *(const float4*)(Bb + (size_t)(n0 + n) * ldb + kt + ka);
      Bs[ka + 0][n] = v.x; Bs[ka + 1][n] = v.y;
      Bs[ka + 2][n] = v.z; Bs[ka + 3][n] = v.w;
    } else {
      int kk = tid >> 4, nc = (tid & 15) * 4;
      float4 v = *(const float4*)(Bb + (size_t)(kt + kk) * ldb + n0 + nc);
      *(float4*)&Bs[kk][nc] = v;
    }
    __syncthreads();
    #pragma unroll
    for (int k = 0; k < BK; ++k) {
      float4 a0 = *(float4*)&As[k][ty * TM];
      float4 a1 = *(float4*)&As[k][ty * TM + 4];
      float4 b0 = *(float4*)&Bs[k][tx * TN];
      float av[TM] = {a0.x, a0.y, a0.z, a0.w, a1.x, a1.y, a1.z, a1.w};
      float bv[TN] = {b0.x, b0.y, b0.z, b0.w};
      #pragma unroll
      for (int i = 0; i < TM; ++i)
        #pragma unroll
        for (int j = 0; j < TN; ++j)
          acc[i][j] = fmaf(av[i], bv[j], acc[i][j]);
    }
    __syncthreads();
  }

  #pragma unroll
  for (int i = 0; i < TM; ++i) {
    int m = m0 + ty * TM + i;
    if (m < M) {
      #pragma unroll
      for (int j = 0; j < TN; ++j) {
        int n = n0 + tx * TN + j;
        float v = acc[i][j];
        if (bias) v += bias[n];
        if constexpr (ADDC) v += Qb[(size_t)m * (size_t)N + n];
        Cb[(size_t)m * (size_t)N + n] = activate<ACT>(v);
      }
    }
  }
}

// WhhT[dir][k][r] = Whh_dir[r][k]   (k<256 hidden, r<1024 gate-row)
__global__ __launch_bounds__(256) void whh_transpose(
    const float* __restrict__ Wf, const float* __restrict__ Wb, float* __restrict__ WhhT)
{
  int n = blockIdx.x * 256 + threadIdx.x;
  if (n >= 2 * H_ * G4) return;
  int dir = n >> 18;
  int e = n & (H_ * G4 - 1);
  int k = e >> 10;
  int r = e & (G4 - 1);
  const float* W = dir ? Wb : Wf;
  WhhT[n] = W[r * H_ + k];
}

// 64 blocks x 1024 threads. dir = bid>>5, 2 batch elements per block.
// K dimension split 4 ways (quarter q = tid>>8); partials reduced in LDS.
__global__ __launch_bounds__(1024) void lstm_rec(
    const float* __restrict__ GX, const float* __restrict__ WhhT,
    const int* __restrict__ lens, float* __restrict__ out)
{
  const int bid = blockIdx.x;
  const int dir = bid >> 5;
  const int pr = bid & 31;
  const int b0 = pr * 2, b1 = b0 + 1;
  const int tid = threadIdx.x;
  const int q = tid >> 8;          // k-quarter (wave-uniform)
  const int cq = tid & 255;        // column group
  const int col = cq * 4;
  const float* W = WhhT + (size_t)dir * (H_ * G4);
  const float* gx = GX + (size_t)dir * ((size_t)BS * G4);
  const int len0 = lens[b0], len1 = lens[b1];

  __shared__ float hs0[H_], hs1[H_];
  __shared__ float part0[4][G4];
  __shared__ float part1[4][G4];
  __shared__ float act0[G4], act1[G4];

  if (tid < H_) { hs0[tid] = 0.f; hs1[tid] = 0.f; }
  float c0 = 0.f, c1 = 0.f;   // threads 0..255 carry batch0 c[tid]; 256..511 batch1
  __syncthreads();

  const int k0 = q * 64;
  for (int t = 0; t < S_; ++t) {
    const int pos0 = dir ? (t < len0 ? len0 - 1 - t : t) : t;
    const int pos1 = dir ? (t < len1 ? len1 - 1 - t : t) : t;

    // issue GX loads early (only quarter 0 folds them in); k-loop hides latency
    float4 g0 = make_float4(0.f, 0.f, 0.f, 0.f), g1 = g0;
    if (q == 0) {
      g0 = *(const float4*)(gx + ((size_t)(b0 * S_ + pos0)) * G4 + col);
      g1 = *(const float4*)(gx + ((size_t)(b1 * S_ + pos1)) * G4 + col);
    }

    float4 s0 = make_float4(0.f, 0.f, 0.f, 0.f), s1 = s0;
    const float* wp = W + (size_t)k0 * G4 + col;
    #pragma unroll 8
    for (int kk = 0; kk < 64; ++kk) {
      float4 wv = *(const float4*)wp; wp += G4;
      float h0 = hs0[k0 + kk], h1 = hs1[k0 + kk];
      s0.x = fmaf(h0, wv.x, s0.x); s0.y = fmaf(h0, wv.y, s0.y);
      s0.z = fmaf(h0, wv.z, s0.z); s0.w = fmaf(h0, wv.w, s0.w);
      s1.x = fmaf(h1, wv.x, s1.x); s1.y = fmaf(h1, wv.y, s1.y);
      s1.z = fmaf(h1, wv.z, s1.z); s1.w = fmaf(h1, wv.w, s1.w);
    }
    s0.x += g0.x; s0.y += g0.y; s0.z += g0.z; s0.w += g0.w;
    s1.x += g1.x; s1.y += g1.y; s1.z += g1.z; s1.w += g1.w;
    *(float4*)&part0[q][col] = s0;
    *(float4*)&part1[q][col] = s1;
    __syncthreads();

    // reduce 4 partials + activation; thread j handles gate-column j, both batches
    {
      const int j = tid;
      float v0 = part0[0][j] + part0[1][j] + part0[2][j] + part0[3][j];
      float v1 = part1[0][j] + part1[1][j] + part1[2][j] + part1[3][j];
      if ((j >> 8) == 2) { v0 = tanhf(v0); v1 = tanhf(v1); }
      else { v0 = 1.f / (1.f + expf(-v0)); v1 = 1.f / (1.f + expf(-v1)); }
      act0[j] = v0; act1[j] = v1;
    }
    __syncthreads();

    if (tid < 256) {
      const int j = tid;
      float iv = act0[j], fv = act0[H_ + j], gv = act0[2 * H_ + j], ov = act0[3 * H_ + j];
      float cn = fmaf(fv, c0, iv * gv);
      float hn = ov * tanhf(cn);
      bool v = t < len0;
      if (v) { c0 = cn; hs0[j] = hn; }
      out[((size_t)(b0 * S_ + pos0)) * (2 * H_) + dir * H_ + j] = v ? hn : 0.f;
    } else if (tid < 512) {
      const int j = tid - 256;
      float iv = act1[j], fv = act1[H_ + j], gv = act1[2 * H_ + j], ov = act1[3 * H_ + j];
      float cn = fmaf(fv, c1, iv * gv);
      float hn = ov * tanhf(cn);
      bool v = t < len1;
      if (v) { c1 = cn; hs1[j] = hn; }
      out[((size_t)(b1 * S_ + pos1)) * (2 * H_) + dir * H_ + j] = v ? hn : 0.f;
    }
    __syncthreads();
  }
}

__global__ __launch_bounds__(512) void asps_k(
    const float* __restrict__ lstm, const float* __restrict__ amask,
    const int* __restrict__ alen, float* __restrict__ asps)
{
  int b = blockIdx.x, d = threadIdx.x;
  float acc = 0.f;
  for (int t = 0; t < S_; ++t)
    if (amask[b * S_ + t] == 0.f) acc += lstm[((size_t)(b * S_ + t)) * D_ + d];
  asps[b * D_ + d] = acc / (float)alen[b];
}

// softmax over rows of score (B*S rows of length S), adding asps_mask[b,:]
__global__ __launch_bounds__(256) void softmax_rows(
    float* __restrict__ p_, const float* __restrict__ mask)
{
  const int row = blockIdx.x;
  const int b = row >> 8;
  const int tid = threadIdx.x;
  float* p = p_ + (size_t)row * S_;
  float v = p[tid] + mask[(b << 8) | tid];
  float m = v;
  #pragma unroll
  for (int off = 32; off > 0; off >>= 1) m = fmaxf(m, __shfl_xor(m, off));
  __shared__ float r1[4];
  __shared__ float r2[4];
  const int w = tid >> 6, l = tid & 63;
  if (l == 0) r1[w] = m;
  __syncthreads();
  m = fmaxf(fmaxf(r1[0], r1[1]), fmaxf(r1[2], r1[3]));
  float e = expf(v - m);
  float s = e;
  #pragma unroll
  for (int off = 32; off > 0; off >>= 1) s += __shfl_xor(s, off);
  if (l == 0) r2[w] = s;
  __syncthreads();
  s = r2[0] + r2[1] + r2[2] + r2[3];
  p[tid] = e / s;
}

// x_out = scale*lin + (1-scale)*x_in
__global__ __launch_bounds__(256) void xupdate(
    const float4* __restrict__ xin, const float4* __restrict__ sc,
    const float4* __restrict__ lin, float4* __restrict__ xout, int n4)
{
  int i = blockIdx.x * 256 + threadIdx.x;
  if (i < n4) {
    float4 s = sc[i], l = lin[i], xv = xin[i], o;
    o.x = s.x * l.x + (1.f - s.x) * xv.x;
    o.y = s.y * l.y + (1.f - s.y) * xv.y;
    o.z = s.z * l.z + (1.f - s.z) * xv.z;
    o.w = s.w * l.w + (1.f - s.w) * xv.w;
    xout[i] = o;
  }
}

// sc[b,k] = softmax_k( dot(Qp[b], Kp[b,k]) / sqrt(512) + sent_mask[b,k] )
__global__ __launch_bounds__(256) void final_sc_k(
    const float* __restrict__ Qp, const float* __restrict__ Kp,
    const float* __restrict__ smask, float* __restrict__ outsc)
{
  int b = blockIdx.x, tid = threadIdx.x;
  __shared__ float q[D_];
  q[tid] = Qp[b * D_ + tid];
  q[tid + 256] = Qp[b * D_ + tid + 256];
  __syncthreads();
  const float4* kr = (const float4*)(Kp + ((size_t)(b * S_ + tid)) * D_);
  float acc = 0.f;
  #pragma unroll 4
  for (int d = 0; d < D_ / 4; ++d) {
    float4 kv = kr[d];
    acc += q[4 * d] * kv.x + q[4 * d + 1] * kv.y + q[4 * d + 2] * kv.z + q[4 * d + 3] * kv.w;
  }
  float v = acc / sqrtf((float)D_) + smask[b * S_ + tid];
  float m = v;
  #pragma unroll
  for (int off = 32; off > 0; off >>= 1) m = fmaxf(m, __shfl_xor(m, off));
  __shared__ float r1[4];
  __shared__ float r2[4];
  const int w = tid >> 6, l = tid & 63;
  if (l == 0) r1[w] = m;
  __syncthreads();
  m = fmaxf(fmaxf(r1[0], r1[1]), fmaxf(r1[2], r1[3]));
  float e = expf(v - m);
  float s = e;
  #pragma unroll
  for (int off = 32; off > 0; off >>= 1) s += __shfl_xor(s, off);
  if (l == 0) r2[w] = s;
  __syncthreads();
  s = r2[0] + r2[1] + r2[2] + r2[3];
  outsc[b * S_ + tid] = e / s;
}

__global__ __launch_bounds__(512) void out_vec_k(
    const float* __restrict__ sc, const float* __restrict__ Vp, float* __restrict__ outv)
{
  int b = blockIdx.x, d = threadIdx.x;
  __shared__ float s[S_];
  if (d < S_) s[d] = sc[b * S_ + d];
  __syncthreads();
  float acc = 0.f;
  for (int k = 0; k < S_; ++k) acc = fmaf(s[k], Vp[((size_t)(b * S_ + k)) * D_ + d], acc);
  outv[b * D_ + d] = acc;
}

__global__ __launch_bounds__(192) void logits_k(
    const float* __restrict__ outv, const float* __restrict__ Wd,
    const float* __restrict__ bd, float* __restrict__ out)
{
  int b = blockIdx.x;
  int c = threadIdx.x >> 6, l = threadIdx.x & 63;
  float acc = 0.f;
  for (int d = l; d < D_; d += 64) acc = fmaf(outv[b * D_ + d], Wd[c * D_ + d], acc);
  #pragma unroll
  for (int off = 32; off > 0; off >>= 1) acc += __shfl_down(acc, off);
  if (l == 0) out[b * NC_ + c] = acc + bd[c];
}

extern "C" void kernel_launch(void* const* d_in, const int* in_sizes, int n_in,
                              void* d_out, int out_size, void* d_ws, size_t ws_size,
                              hipStream_t stream)
{
  const int*   seqs_id   = (const int*)d_in[0];
  const int*   seqs_len  = (const int*)d_in[1];
  const int*   asps_len  = (const int*)d_in[2];
  const float* asps_mask = (const float*)d_in[3];
  const float* sent_mask = (const float*)d_in[4];
  const float* embed     = (const float*)d_in[5];
  const float* Wih_f     = (const float*)d_in[6];
  const float* Whh_f     = (const float*)d_in[7];
  const float* b_f       = (const float*)d_in[8];
  const float* Wih_b     = (const float*)d_in[9];
  const float* Whh_b     = (const float*)d_in[10];
  const float* b_b       = (const float*)d_in[11];
  const float* W_cpt     = (const float*)d_in[12];
  const float* b_cpt     = (const float*)d_in[13];
  const float* W_as      = (const float*)d_in[14];
  const float* b_as      = (const float*)d_in[15];
  const float* Wq        = (const float*)d_in[16];
  const float* bq        = (const float*)d_in[17];
  const float* Wk        = (const float*)d_in[18];
  const float* bk        = (const float*)d_in[19];
  const float* Wv        = (const float*)d_in[20];
  const float* bv        = (const float*)d_in[21];
  const float* Wd        = (const float*)d_in[22];
  const float* bd        = (const float*)d_in[23];

  float* w = (float*)d_ws;
  const size_t off_whht  = 0;
  const size_t off_gx    = off_whht + 2ul * H_ * G4;            // 524288
  const size_t off_lstm  = off_gx + 2ul * BS * G4;              // GX: 33.55M floats
  const size_t off_x     = off_lstm + (size_t)BS * D_;
  const size_t off_score = off_x + (size_t)BS * D_;
  const size_t off_asps  = off_score + (size_t)B_ * S_ * S_;
  const size_t off_qp    = off_asps + (size_t)B_ * D_;
  const size_t off_outv  = off_qp + (size_t)B_ * D_;
  // overlays on GX region (GX dead after lstm_rec):
  const size_t off_attn  = off_gx;
  const size_t off_lin   = off_gx + (size_t)BS * D_;
  const size_t off_scale = off_gx + 2ul * BS * D_;

  float* WhhT  = w + off_whht;
  float* GX    = w + off_gx;
  float* lstm  = w + off_lstm;
  float* xbuf  = w + off_x;
  float* score = w + off_score;
  float* aspsb = w + off_asps;
  float* qp    = w + off_qp;
  float* outv  = w + off_outv;
  float* attn  = w + off_attn;
  float* lin   = w + off_lin;
  float* scl   = w + off_scale;
  float* logits = (float*)d_out;
  float* outsc  = (float*)d_out + B_ * NC_;

  whh_transpose<<<2048, 256, 0, stream>>>(Whh_f, Whh_b, WhhT);

  // input GEMMs with fused embedding gather; bias folded in
  gemm_k<0, true, false, true><<<dim3(BS / 128, G4 / 64, 1), 256, 0, stream>>>(
      embed, Wih_f, b_f, nullptr, GX, BS, G4, D_, D_, 0, 0, 0, seqs_id);
  gemm_k<0, true, false, true><<<dim3(BS / 128, G4 / 64, 1), 256, 0, stream>>>(
      embed, Wih_b, b_b, nullptr, GX + (size_t)BS * G4, BS, G4, D_, D_, 0, 0, 0, seqs_id);

  lstm_rec<<<64, 1024, 0, stream>>>(GX, WhhT, seqs_len, lstm);
  asps_k<<<B_, D_, 0, stream>>>(lstm, asps_mask, asps_len, aspsb);

  for (int it = 0; it < 2; ++it) {
    const float* xin = (it == 0) ? lstm : xbuf;
    gemm_k<0, true, false, false><<<dim3(2, 4, B_), 256, 0, stream>>>(
        xin, lstm, nullptr, nullptr, score, S_, S_, D_, D_,
        (long)S_ * D_, (long)S_ * D_, (long)S_ * S_, nullptr);
    softmax_rows<<<BS, 256, 0, stream>>>(score, asps_mask);
    gemm_k<0, false, false, false><<<dim3(2, 8, B_), 256, 0, stream>>>(
        score, lstm, nullptr, nullptr, attn, S_, D_, S_, D_,
        (long)S_ * S_, (long)S_ * D_, (long)S_ * D_, nullptr);
    // linear_out = relu(attn @ Wc[:, :512]^T + x @ Wc[:, 512:]^T + b_cpt)
    gemm_k<0, true, false, false><<<dim3(BS / 128, D_ / 64, 1), 256, 0, stream>>>(
        attn, W_cpt, b_cpt, nullptr, lin, BS, D_, D_, 2 * D_, 0, 0, 0, nullptr);
    gemm_k<1, true, true, false><<<dim3(BS / 128, D_ / 64, 1), 256, 0, stream>>>(
        xin, W_cpt + D_, nullptr, lin, lin, BS, D_, D_, 2 * D_, 0, 0, 0, nullptr);
    gemm_k<2, true, false, false><<<dim3(BS / 128, D_ / 64, 1), 256, 0, stream>>>(
        xin, W_as, b_as, nullptr, scl, BS, D_, D_, D_, 0, 0, 0, nullptr);
    xupdate<<<(BS * D_ / 4 + 255) / 256, 256, 0, stream>>>(
        (const float4*)xin, (const float4*)scl, (const float4*)lin, (float4*)xbuf, BS * D_ / 4);
  }

  float* Kp = attn;   // reuse (attn/lin dead after CPT)
  float* Vp = lin;
  gemm_k<0, true, false, false><<<dim3(BS / 128, D_ / 64, 1), 256, 0, stream>>>(
      xbuf, Wk, bk, nullptr, Kp, BS, D_, D_, D_, 0, 0, 0, nullptr);
  gemm_k<0, true, false, false><<<dim3(BS / 128, D_ / 64, 1), 256, 0, stream>>>(
      xbuf, Wv, bv, nullptr, Vp, BS, D_, D_, D_, 0, 0, 0, nullptr);
  gemm_k<0, true, false, false><<<dim3(1, D_ / 64, 1), 256, 0, stream>>>(
      aspsb, Wq, bq, nullptr, qp, B_, D_, D_, D_, 0, 0, 0, nullptr);

  final_sc_k<<<B_, 256, 0, stream>>>(qp, Kp, sent_mask, outsc);
  out_vec_k<<<B_, D_, 0, stream>>>(outsc, Vp, outv);
  logits_k<<<B_, 192, 0, stream>>>(outv, Wd, bd, logits);
}

// Round 3
// 2915.503 us; speedup vs baseline: 1.4935x; 1.3740x over previous
//
#include <hip/hip_runtime.h>
#include <math.h>

constexpr int B_ = 64, S_ = 256, D_ = 512, H_ = 256, NC_ = 3;
constexpr int BS = B_ * S_;     // 16384
constexpr int G4 = 4 * H_;      // 1024

typedef __attribute__((ext_vector_type(4))) float f32x4;
typedef __attribute__((ext_vector_type(8))) short s16x8;
typedef unsigned short u16;

template<int ACT>
static __device__ __forceinline__ float activate(float v) {
  if constexpr (ACT == 1) return v > 0.f ? v : 0.f;
  else if constexpr (ACT == 2) return 1.f / (1.f + expf(-v));
  else return v;
}

static __device__ __forceinline__ u16 f2bf_rne(float f) {
  unsigned u = __float_as_uint(f);
  return (u16)((u + 0x7FFFu + ((u >> 16) & 1u)) >> 16);
}
static __device__ __forceinline__ float bf2f(u16 h) {
  return __uint_as_float(((unsigned)h) << 16);
}
static __device__ __forceinline__ void splitf(float f, u16& h, u16& l) {
  h = f2bf_rne(f);
  float r = f - bf2f(h);
  l = f2bf_rne(r);
}

// ---------------- split precompute kernels ----------------
__global__ __launch_bounds__(256) void split_w(
    const float* __restrict__ src, u16* __restrict__ h, u16* __restrict__ l, int n4)
{
  int i = blockIdx.x * 256 + threadIdx.x;
  if (i >= n4) return;
  float4 v = ((const float4*)src)[i];
  ushort4 hh, ll;
  splitf(v.x, hh.x, ll.x); splitf(v.y, hh.y, ll.y);
  splitf(v.z, hh.z, ll.z); splitf(v.w, hh.w, ll.w);
  ((ushort4*)h)[i] = hh;
  ((ushort4*)l)[i] = ll;
}

// Xemb[m][k] = embed[gidx[m]][k]  (split)
__global__ __launch_bounds__(256) void gather_split(
    const float* __restrict__ embed, const int* __restrict__ gidx,
    u16* __restrict__ h, u16* __restrict__ l)
{
  int i = blockIdx.x * 256 + threadIdx.x;   // over BS*D/4
  if (i >= BS * D_ / 4) return;
  int r = i >> 7;            // row (D/4 = 128 float4 per row)
  int c = (i & 127) << 2;
  float4 v = *(const float4*)(embed + (size_t)gidx[r] * D_ + c);
  ushort4 hh, ll;
  splitf(v.x, hh.x, ll.x); splitf(v.y, hh.y, ll.y);
  splitf(v.z, hh.z, ll.z); splitf(v.w, hh.w, ll.w);
  ((ushort4*)h)[i] = hh;
  ((ushort4*)l)[i] = ll;
}

// ---------------- split-bf16 MFMA GEMM ----------------
// C[M,N] = act( A[M,K] @ B' + bias + (ADDC?Cin:0) )
// A source: ASPL ? (Ah,Al bf16 split, row-major MxK) : Af fp32 row-major
// B source: BT: rows are N, k-contiguous (ldb = k-stride). !BT: B is KxN (BSPL only).
// Output: OSPL ? split (Oh,Ol) : fp32 Co.
template<int ACT, bool BT, bool ADDC, bool ASPL, bool BSPL, bool OSPL>
__global__ __launch_bounds__(256) void mgemm(
    const float* __restrict__ Af, const u16* __restrict__ Ah, const u16* __restrict__ Al,
    const float* __restrict__ Bf, const u16* __restrict__ Bh, const u16* __restrict__ Bl,
    const float* __restrict__ bias, const float* __restrict__ Cin,
    float* __restrict__ Co, u16* __restrict__ Oh, u16* __restrict__ Ol,
    int M, int N, int K, int ldb, long sA, long sB, long sC)
{
  __shared__ u16 AH[128][40];
  __shared__ u16 AL[128][40];
  __shared__ u16 BH[64][40];
  __shared__ u16 BL[64][40];

  const int tid = threadIdx.x;
  const int w = tid >> 6, l = tid & 63;
  const int m0 = blockIdx.x * 128, n0 = blockIdx.y * 64;
  const long zA = (long)blockIdx.z * sA;
  const long zB = (long)blockIdx.z * sB;
  const long zC = (long)blockIdx.z * sC;

  f32x4 acc[2][4];
  #pragma unroll
  for (int i = 0; i < 2; ++i)
    #pragma unroll
    for (int j = 0; j < 4; ++j) acc[i][j] = (f32x4){0.f, 0.f, 0.f, 0.f};

  const int ar = tid >> 1, ahh = tid & 1;        // A staging: row, k-half
  const int bn = tid >> 2, bq = tid & 3;         // B staging (BT)
  const int bk = tid >> 3, bnq = tid & 7;        // B staging (!BT)
  const int lr = l & 15, lk = (l >> 4) * 8;      // fragment lane offsets

  for (int kt = 0; kt < K; kt += 32) {
    // ---- stage A ----
    {
      int m = m0 + ar;
      if constexpr (ASPL) {
        s16x8 h0 = (s16x8)0, h1 = (s16x8)0, l0 = (s16x8)0, l1 = (s16x8)0;
        if (m < M) {
          const u16* ph = Ah + zA + (size_t)m * K + kt + ahh * 16;
          const u16* pl = Al + zA + (size_t)m * K + kt + ahh * 16;
          h0 = *(const s16x8*)ph; h1 = *(const s16x8*)(ph + 8);
          l0 = *(const s16x8*)pl; l1 = *(const s16x8*)(pl + 8);
        }
        *(s16x8*)&AH[ar][ahh * 16] = h0; *(s16x8*)&AH[ar][ahh * 16 + 8] = h1;
        *(s16x8*)&AL[ar][ahh * 16] = l0; *(s16x8*)&AL[ar][ahh * 16 + 8] = l1;
      } else {
        float vv[16];
        if (m < M) {
          const float* pf = Af + zA + (size_t)m * K + kt + ahh * 16;
          #pragma unroll
          for (int c = 0; c < 4; ++c) {
            float4 v = ((const float4*)pf)[c];
            vv[c * 4] = v.x; vv[c * 4 + 1] = v.y; vv[c * 4 + 2] = v.z; vv[c * 4 + 3] = v.w;
          }
        } else {
          #pragma unroll
          for (int c = 0; c < 16; ++c) vv[c] = 0.f;
        }
        u16 hh[16], ll[16];
        #pragma unroll
        for (int c = 0; c < 16; ++c) splitf(vv[c], hh[c], ll[c]);
        *(s16x8*)&AH[ar][ahh * 16] = *(s16x8*)&hh[0];
        *(s16x8*)&AH[ar][ahh * 16 + 8] = *(s16x8*)&hh[8];
        *(s16x8*)&AL[ar][ahh * 16] = *(s16x8*)&ll[0];
        *(s16x8*)&AL[ar][ahh * 16 + 8] = *(s16x8*)&ll[8];
      }
    }
    // ---- stage B ----
    if constexpr (BT) {
      if constexpr (BSPL) {
        const u16* ph = Bh + zB + (size_t)(n0 + bn) * ldb + kt + bq * 8;
        const u16* pl = Bl + zB + (size_t)(n0 + bn) * ldb + kt + bq * 8;
        *(s16x8*)&BH[bn][bq * 8] = *(const s16x8*)ph;
        *(s16x8*)&BL[bn][bq * 8] = *(const s16x8*)pl;
      } else {
        const float* pf = Bf + zB + (size_t)(n0 + bn) * ldb + kt + bq * 8;
        float vv[8];
        #pragma unroll
        for (int c = 0; c < 2; ++c) {
          float4 v = ((const float4*)pf)[c];
          vv[c * 4] = v.x; vv[c * 4 + 1] = v.y; vv[c * 4 + 2] = v.z; vv[c * 4 + 3] = v.w;
        }
        u16 hh[8], ll[8];
        #pragma unroll
        for (int c = 0; c < 8; ++c) splitf(vv[c], hh[c], ll[c]);
        *(s16x8*)&BH[bn][bq * 8] = *(s16x8*)&hh[0];
        *(s16x8*)&BL[bn][bq * 8] = *(s16x8*)&ll[0];
      }
    } else {
      // B is KxN, BSPL required
      const u16* ph = Bh + zB + (size_t)(kt + bk) * ldb + n0 + bnq * 8;
      const u16* pl = Bl + zB + (size_t)(kt + bk) * ldb + n0 + bnq * 8;
      s16x8 h8 = *(const s16x8*)ph;
      s16x8 l8 = *(const s16x8*)pl;
      #pragma unroll
      for (int j = 0; j < 8; ++j) {
        BH[bnq * 8 + j][bk] = (u16)h8[j];
        BL[bnq * 8 + j][bk] = (u16)l8[j];
      }
    }
    __syncthreads();

    // ---- fragments + MFMA ----
    s16x8 afh[2], afl[2], bfh[4], bfl[4];
    #pragma unroll
    for (int i = 0; i < 2; ++i) {
      afh[i] = *(const s16x8*)&AH[w * 32 + i * 16 + lr][lk];
      afl[i] = *(const s16x8*)&AL[w * 32 + i * 16 + lr][lk];
    }
    #pragma unroll
    for (int j = 0; j < 4; ++j) {
      bfh[j] = *(const s16x8*)&BH[j * 16 + lr][lk];
      bfl[j] = *(const s16x8*)&BL[j * 16 + lr][lk];
    }
    #pragma unroll
    for (int i = 0; i < 2; ++i)
      #pragma unroll
      for (int j = 0; j < 4; ++j) {
        acc[i][j] = __builtin_amdgcn_mfma_f32_16x16x32_bf16(afl[i], bfh[j], acc[i][j], 0, 0, 0);
        acc[i][j] = __builtin_amdgcn_mfma_f32_16x16x32_bf16(afh[i], bfl[j], acc[i][j], 0, 0, 0);
        acc[i][j] = __builtin_amdgcn_mfma_f32_16x16x32_bf16(afh[i], bfh[j], acc[i][j], 0, 0, 0);
      }
    __syncthreads();
  }

  // ---- epilogue: C[row=(l>>4)*4+e][col=l&15] per 16x16 fragment ----
  const int rl = (l >> 4) * 4;
  #pragma unroll
  for (int j = 0; j < 4; ++j) {
    int n = n0 + j * 16 + lr;
    float bv = bias ? bias[n] : 0.f;
    #pragma unroll
    for (int i = 0; i < 2; ++i) {
      #pragma unroll
      for (int e = 0; e < 4; ++e) {
        int m = m0 + w * 32 + i * 16 + rl + e;
        if (m < M) {
          float v = acc[i][j][e] + bv;
          if constexpr (ADDC) v += Cin[zC + (size_t)m * N + n];
          v = activate<ACT>(v);
          if constexpr (OSPL) {
            u16 hh, ll; splitf(v, hh, ll);
            Oh[zC + (size_t)m * N + n] = hh;
            Ol[zC + (size_t)m * N + n] = ll;
          } else {
            Co[zC + (size_t)m * N + n] = v;
          }
        }
      }
    }
  }
}

// WhhT[dir][k][r] = Whh_dir[r][k]
__global__ __launch_bounds__(256) void whh_transpose(
    const float* __restrict__ Wf, const float* __restrict__ Wb, float* __restrict__ WhhT)
{
  int n = blockIdx.x * 256 + threadIdx.x;
  if (n >= 2 * H_ * G4) return;
  int dir = n >> 18;
  int e = n & (H_ * G4 - 1);
  int k = e >> 10;
  int r = e & (G4 - 1);
  const float* W = dir ? Wb : Wf;
  WhhT[n] = W[r * H_ + k];
}

// 64 blocks x 1024 threads; emits split-bf16 lstm output.
__global__ __launch_bounds__(1024) void lstm_rec(
    const float* __restrict__ GX, const float* __restrict__ WhhT,
    const int* __restrict__ lens, u16* __restrict__ outH, u16* __restrict__ outL)
{
  const int bid = blockIdx.x;
  const int dir = bid >> 5;
  const int pr = bid & 31;
  const int b0 = pr * 2, b1 = b0 + 1;
  const int tid = threadIdx.x;
  const int q = tid >> 8;
  const int cq = tid & 255;
  const int col = cq * 4;
  const float* W = WhhT + (size_t)dir * (H_ * G4);
  const float* gx = GX + (size_t)dir * ((size_t)BS * G4);
  const int len0 = lens[b0], len1 = lens[b1];

  __shared__ float hs0[H_], hs1[H_];
  __shared__ float part0[4][G4];
  __shared__ float part1[4][G4];
  __shared__ float act0[G4], act1[G4];

  if (tid < H_) { hs0[tid] = 0.f; hs1[tid] = 0.f; }
  float c0 = 0.f, c1 = 0.f;
  __syncthreads();

  const int k0 = q * 64;
  for (int t = 0; t < S_; ++t) {
    const int pos0 = dir ? (t < len0 ? len0 - 1 - t : t) : t;
    const int pos1 = dir ? (t < len1 ? len1 - 1 - t : t) : t;

    float4 g0 = make_float4(0.f, 0.f, 0.f, 0.f), g1 = g0;
    if (q == 0) {
      g0 = *(const float4*)(gx + ((size_t)(b0 * S_ + pos0)) * G4 + col);
      g1 = *(const float4*)(gx + ((size_t)(b1 * S_ + pos1)) * G4 + col);
    }

    float4 s0 = make_float4(0.f, 0.f, 0.f, 0.f), s1 = s0;
    const float* wp = W + (size_t)k0 * G4 + col;
    #pragma unroll 8
    for (int kk = 0; kk < 64; ++kk) {
      float4 wv = *(const float4*)wp; wp += G4;
      float h0 = hs0[k0 + kk], h1 = hs1[k0 + kk];
      s0.x = fmaf(h0, wv.x, s0.x); s0.y = fmaf(h0, wv.y, s0.y);
      s0.z = fmaf(h0, wv.z, s0.z); s0.w = fmaf(h0, wv.w, s0.w);
      s1.x = fmaf(h1, wv.x, s1.x); s1.y = fmaf(h1, wv.y, s1.y);
      s1.z = fmaf(h1, wv.z, s1.z); s1.w = fmaf(h1, wv.w, s1.w);
    }
    s0.x += g0.x; s0.y += g0.y; s0.z += g0.z; s0.w += g0.w;
    s1.x += g1.x; s1.y += g1.y; s1.z += g1.z; s1.w += g1.w;
    *(float4*)&part0[q][col] = s0;
    *(float4*)&part1[q][col] = s1;
    __syncthreads();

    {
      const int j = tid;
      float v0 = part0[0][j] + part0[1][j] + part0[2][j] + part0[3][j];
      float v1 = part1[0][j] + part1[1][j] + part1[2][j] + part1[3][j];
      if ((j >> 8) == 2) { v0 = tanhf(v0); v1 = tanhf(v1); }
      else { v0 = 1.f / (1.f + expf(-v0)); v1 = 1.f / (1.f + expf(-v1)); }
      act0[j] = v0; act1[j] = v1;
    }
    __syncthreads();

    if (tid < 256) {
      const int j = tid;
      float iv = act0[j], fv = act0[H_ + j], gv = act0[2 * H_ + j], ov = act0[3 * H_ + j];
      float cn = fmaf(fv, c0, iv * gv);
      float hn = ov * tanhf(cn);
      bool v = t < len0;
      if (v) { c0 = cn; hs0[j] = hn; }
      float o = v ? hn : 0.f;
      size_t idx = ((size_t)(b0 * S_ + pos0)) * (2 * H_) + dir * H_ + j;
      u16 hh, ll; splitf(o, hh, ll);
      outH[idx] = hh; outL[idx] = ll;
    } else if (tid < 512) {
      const int j = tid - 256;
      float iv = act1[j], fv = act1[H_ + j], gv = act1[2 * H_ + j], ov = act1[3 * H_ + j];
      float cn = fmaf(fv, c1, iv * gv);
      float hn = ov * tanhf(cn);
      bool v = t < len1;
      if (v) { c1 = cn; hs1[j] = hn; }
      float o = v ? hn : 0.f;
      size_t idx = ((size_t)(b1 * S_ + pos1)) * (2 * H_) + dir * H_ + j;
      u16 hh, ll; splitf(o, hh, ll);
      outH[idx] = hh; outL[idx] = ll;
    }
    __syncthreads();
  }
}

__global__ __launch_bounds__(512) void asps_k(
    const u16* __restrict__ lh, const u16* __restrict__ ll,
    const float* __restrict__ amask, const int* __restrict__ alen, float* __restrict__ asps)
{
  int b = blockIdx.x, d = threadIdx.x;
  float acc = 0.f;
  for (int t = 0; t < S_; ++t)
    if (amask[b * S_ + t] == 0.f) {
      size_t i = ((size_t)(b * S_ + t)) * D_ + d;
      acc += bf2f(lh[i]) + bf2f(ll[i]);
    }
  asps[b * D_ + d] = acc / (float)alen[b];
}

// softmax over rows (B*S rows of len S); reads f32 scores, emits split-bf16 p.
__global__ __launch_bounds__(256) void softmax_rows(
    const float* __restrict__ p_, const float* __restrict__ mask,
    u16* __restrict__ ph, u16* __restrict__ pl)
{
  const int row = blockIdx.x;
  const int b = row >> 8;
  const int tid = threadIdx.x;
  const float* p = p_ + (size_t)row * S_;
  float v = p[tid] + mask[(b << 8) | tid];
  float m = v;
  #pragma unroll
  for (int off = 32; off > 0; off >>= 1) m = fmaxf(m, __shfl_xor(m, off));
  __shared__ float r1[4];
  __shared__ float r2[4];
  const int w = tid >> 6, l = tid & 63;
  if (l == 0) r1[w] = m;
  __syncthreads();
  m = fmaxf(fmaxf(r1[0], r1[1]), fmaxf(r1[2], r1[3]));
  float e = expf(v - m);
  float s = e;
  #pragma unroll
  for (int off = 32; off > 0; off >>= 1) s += __shfl_xor(s, off);
  if (l == 0) r2[w] = s;
  __syncthreads();
  s = r2[0] + r2[1] + r2[2] + r2[3];
  float o = e / s;
  u16 hh, ll; splitf(o, hh, ll);
  ph[(size_t)row * S_ + tid] = hh;
  pl[(size_t)row * S_ + tid] = ll;
}

// x_out = scale*lin + (1-scale)*x_in   (x in/out split-bf16)
__global__ __launch_bounds__(256) void xupdate(
    const u16* __restrict__ xh, const u16* __restrict__ xl,
    const float4* __restrict__ sc, const float4* __restrict__ lin,
    u16* __restrict__ oh, u16* __restrict__ ol, int n4)
{
  int i = blockIdx.x * 256 + threadIdx.x;
  if (i >= n4) return;
  ushort4 h4 = ((const ushort4*)xh)[i];
  ushort4 l4 = ((const ushort4*)xl)[i];
  float4 s = sc[i], lv = lin[i];
  float x0 = bf2f(h4.x) + bf2f(l4.x);
  float x1 = bf2f(h4.y) + bf2f(l4.y);
  float x2 = bf2f(h4.z) + bf2f(l4.z);
  float x3 = bf2f(h4.w) + bf2f(l4.w);
  float o0 = s.x * lv.x + (1.f - s.x) * x0;
  float o1 = s.y * lv.y + (1.f - s.y) * x1;
  float o2 = s.z * lv.z + (1.f - s.z) * x2;
  float o3 = s.w * lv.w + (1.f - s.w) * x3;
  ushort4 hh, ll;
  splitf(o0, hh.x, ll.x); splitf(o1, hh.y, ll.y);
  splitf(o2, hh.z, ll.z); splitf(o3, hh.w, ll.w);
  ((ushort4*)oh)[i] = hh;
  ((ushort4*)ol)[i] = ll;
}

__global__ __launch_bounds__(256) void final_sc_k(
    const float* __restrict__ Qp, const float* __restrict__ Kp,
    const float* __restrict__ smask, float* __restrict__ outsc)
{
  int b = blockIdx.x, tid = threadIdx.x;
  __shared__ float q[D_];
  q[tid] = Qp[b * D_ + tid];
  q[tid + 256] = Qp[b * D_ + tid + 256];
  __syncthreads();
  const float4* kr = (const float4*)(Kp + ((size_t)(b * S_ + tid)) * D_);
  float acc = 0.f;
  #pragma unroll 4
  for (int d = 0; d < D_ / 4; ++d) {
    float4 kv = kr[d];
    acc += q[4 * d] * kv.x + q[4 * d + 1] * kv.y + q[4 * d + 2] * kv.z + q[4 * d + 3] * kv.w;
  }
  float v = acc / sqrtf((float)D_) + smask[b * S_ + tid];
  float m = v;
  #pragma unroll
  for (int off = 32; off > 0; off >>= 1) m = fmaxf(m, __shfl_xor(m, off));
  __shared__ float r1[4];
  __shared__ float r2[4];
  const int w = tid >> 6, l = tid & 63;
  if (l == 0) r1[w] = m;
  __syncthreads();
  m = fmaxf(fmaxf(r1[0], r1[1]), fmaxf(r1[2], r1[3]));
  float e = expf(v - m);
  float s = e;
  #pragma unroll
  for (int off = 32; off > 0; off >>= 1) s += __shfl_xor(s, off);
  if (l == 0) r2[w] = s;
  __syncthreads();
  s = r2[0] + r2[1] + r2[2] + r2[3];
  outsc[b * S_ + tid] = e / s;
}

__global__ __launch_bounds__(512) void out_vec_k(
    const float* __restrict__ sc, const float* __restrict__ Vp, float* __restrict__ outv)
{
  int b = blockIdx.x, d = threadIdx.x;
  __shared__ float s[S_];
  if (d < S_) s[d] = sc[b * S_ + d];
  __syncthreads();
  float acc = 0.f;
  for (int k = 0; k < S_; ++k) acc = fmaf(s[k], Vp[((size_t)(b * S_ + k)) * D_ + d], acc);
  outv[b * D_ + d] = acc;
}

__global__ __launch_bounds__(192) void logits_k(
    const float* __restrict__ outv, const float* __restrict__ Wd,
    const float* __restrict__ bd, float* __restrict__ out)
{
  int b = blockIdx.x;
  int c = threadIdx.x >> 6, l = threadIdx.x & 63;
  float acc = 0.f;
  for (int d = l; d < D_; d += 64) acc = fmaf(outv[b * D_ + d], Wd[c * D_ + d], acc);
  #pragma unroll
  for (int off = 32; off > 0; off >>= 1) acc += __shfl_down(acc, off);
  if (l == 0) out[b * NC_ + c] = acc + bd[c];
}

extern "C" void kernel_launch(void* const* d_in, const int* in_sizes, int n_in,
                              void* d_out, int out_size, void* d_ws, size_t ws_size,
                              hipStream_t stream)
{
  const int*   seqs_id   = (const int*)d_in[0];
  const int*   seqs_len  = (const int*)d_in[1];
  const int*   asps_len  = (const int*)d_in[2];
  const float* asps_mask = (const float*)d_in[3];
  const float* sent_mask = (const float*)d_in[4];
  const float* embed     = (const float*)d_in[5];
  const float* Wih_f     = (const float*)d_in[6];
  const float* Whh_f     = (const float*)d_in[7];
  const float* b_f       = (const float*)d_in[8];
  const float* Wih_b     = (const float*)d_in[9];
  const float* Whh_b     = (const float*)d_in[10];
  const float* b_b       = (const float*)d_in[11];
  const float* W_cpt     = (const float*)d_in[12];
  const float* b_cpt     = (const float*)d_in[13];
  const float* W_as      = (const float*)d_in[14];
  const float* b_as      = (const float*)d_in[15];
  const float* Wq        = (const float*)d_in[16];
  const float* bq        = (const float*)d_in[17];
  const float* Wk        = (const float*)d_in[18];
  const float* bk        = (const float*)d_in[19];
  const float* Wv        = (const float*)d_in[20];
  const float* bv        = (const float*)d_in[21];
  const float* Wd        = (const float*)d_in[22];
  const float* bd        = (const float*)d_in[23];

  float* w = (float*)d_ws;
  size_t off = 0;
  auto alloc = [&](size_t words) { size_t o = off; off += words; return o; };

  // split buffer of n elems = n words (hi: n u16, lo: n u16)
  struct Split { u16* h; u16* l; };
  auto salloc = [&](size_t n) {
    size_t o = alloc(n);
    Split s; s.h = (u16*)(w + o); s.l = (u16*)(w + o) + n; return s;
  };

  // ---- persistent ----
  const size_t off_whht = alloc(2ul * H_ * G4);
  Split sWihF = salloc(4ul * H_ * D_);
  Split sWihB = salloc(4ul * H_ * D_);
  Split sWcpt = salloc((size_t)D_ * 2 * D_);
  Split sWas  = salloc((size_t)D_ * D_);
  Split sWk   = salloc((size_t)D_ * D_);
  Split sWv   = salloc((size_t)D_ * D_);
  Split sWq   = salloc((size_t)D_ * D_);
  Split sLstm = salloc((size_t)BS * D_);
  const size_t off_asps = alloc((size_t)B_ * D_);
  const size_t off_qp   = alloc((size_t)B_ * D_);
  const size_t off_outv = alloc((size_t)B_ * D_);

  // ---- dynamic region (phase1 and phase2 overlay) ----
  const size_t dyn0 = off;
  // phase1: XembHL (BS*D words) + GX (2*BS*G4 words)
  Split sXemb; sXemb.h = (u16*)(w + dyn0); sXemb.l = sXemb.h + (size_t)BS * D_;
  float* GX = w + dyn0 + (size_t)BS * D_;
  // phase2 overlays (start at dyn0):
  size_t p2 = dyn0;
  float* scoreF = w + p2;                 p2 += (size_t)B_ * S_ * S_;
  Split sScore; sScore.h = (u16*)(w + p2); sScore.l = sScore.h + (size_t)B_ * S_ * S_; p2 += (size_t)B_ * S_ * S_;
  Split sAttn;  sAttn.h  = (u16*)(w + p2); sAttn.l  = sAttn.h + (size_t)BS * D_;       p2 += (size_t)BS * D_;
  float* lin = w + p2;                    p2 += (size_t)BS * D_;
  float* scl = w + p2;                    p2 += (size_t)BS * D_;
  Split sX;     sX.h     = (u16*)(w + p2); sX.l     = sX.h + (size_t)BS * D_;           p2 += (size_t)BS * D_;

  float* WhhT  = w + off_whht;
  float* aspsb = w + off_asps;
  float* qp    = w + off_qp;
  float* outv  = w + off_outv;
  float* Kp    = (float*)sAttn.h;   // reuse attn region post-CPT
  float* Vp    = lin;               // reuse lin region post-CPT
  float* logits = (float*)d_out;
  float* outsc  = (float*)d_out + B_ * NC_;

  // ---- weight preprocessing ----
  whh_transpose<<<2048, 256, 0, stream>>>(Whh_f, Whh_b, WhhT);
  split_w<<<512, 256, 0, stream>>>(Wih_f, sWihF.h, sWihF.l, H_ * D_);          // 4HD/4
  split_w<<<512, 256, 0, stream>>>(Wih_b, sWihB.h, sWihB.l, H_ * D_);
  split_w<<<512, 256, 0, stream>>>(W_cpt, sWcpt.h, sWcpt.l, D_ * 2 * D_ / 4);
  split_w<<<256, 256, 0, stream>>>(W_as, sWas.h, sWas.l, D_ * D_ / 4);
  split_w<<<256, 256, 0, stream>>>(Wk, sWk.h, sWk.l, D_ * D_ / 4);
  split_w<<<256, 256, 0, stream>>>(Wv, sWv.h, sWv.l, D_ * D_ / 4);
  split_w<<<256, 256, 0, stream>>>(Wq, sWq.h, sWq.l, D_ * D_ / 4);
  gather_split<<<BS * D_ / 4 / 256, 256, 0, stream>>>(embed, seqs_id, sXemb.h, sXemb.l);

  // ---- input GEMMs: GX = Xemb @ Wih^T + b ----
  mgemm<0, true, false, true, true, false><<<dim3(128, 16, 1), 256, 0, stream>>>(
      nullptr, sXemb.h, sXemb.l, nullptr, sWihF.h, sWihF.l, b_f, nullptr,
      GX, nullptr, nullptr, BS, G4, D_, D_, 0, 0, 0);
  mgemm<0, true, false, true, true, false><<<dim3(128, 16, 1), 256, 0, stream>>>(
      nullptr, sXemb.h, sXemb.l, nullptr, sWihB.h, sWihB.l, b_b, nullptr,
      GX + (size_t)BS * G4, nullptr, nullptr, BS, G4, D_, D_, 0, 0, 0);

  lstm_rec<<<64, 1024, 0, stream>>>(GX, WhhT, seqs_len, sLstm.h, sLstm.l);
  asps_k<<<B_, D_, 0, stream>>>(sLstm.h, sLstm.l, asps_mask, asps_len, aspsb);

  for (int it = 0; it < 2; ++it) {
    const Split xin = (it == 0) ? sLstm : sX;
    // score = x @ lstm^T  (batched)
    mgemm<0, true, false, true, true, false><<<dim3(2, 4, B_), 256, 0, stream>>>(
        nullptr, xin.h, xin.l, nullptr, sLstm.h, sLstm.l, nullptr, nullptr,
        scoreF, nullptr, nullptr, S_, S_, D_, D_,
        (long)S_ * D_, (long)S_ * D_, (long)S_ * S_);
    softmax_rows<<<BS, 256, 0, stream>>>(scoreF, asps_mask, sScore.h, sScore.l);
    // attn = p @ lstm  (batched, B KxN) -> split output
    mgemm<0, false, false, true, true, true><<<dim3(2, 8, B_), 256, 0, stream>>>(
        nullptr, sScore.h, sScore.l, nullptr, sLstm.h, sLstm.l, nullptr, nullptr,
        nullptr, sAttn.h, sAttn.l, S_, D_, S_, D_,
        (long)S_ * S_, (long)S_ * D_, (long)S_ * D_);
    // lin = relu(attn @ Wc1^T + x @ Wc2^T + b)
    mgemm<0, true, false, true, true, false><<<dim3(128, 8, 1), 256, 0, stream>>>(
        nullptr, sAttn.h, sAttn.l, nullptr, sWcpt.h, sWcpt.l, b_cpt, nullptr,
        lin, nullptr, nullptr, BS, D_, D_, 2 * D_, 0, 0, 0);
    mgemm<1, true, true, true, true, false><<<dim3(128, 8, 1), 256, 0, stream>>>(
        nullptr, xin.h, xin.l, nullptr, sWcpt.h + D_, sWcpt.l + D_, nullptr, lin,
        lin, nullptr, nullptr, BS, D_, D_, 2 * D_, 0, 0, 0);
    // scl = sigmoid(x @ Was^T + b)
    mgemm<2, true, false, true, true, false><<<dim3(128, 8, 1), 256, 0, stream>>>(
        nullptr, xin.h, xin.l, nullptr, sWas.h, sWas.l, b_as, nullptr,
        scl, nullptr, nullptr, BS, D_, D_, D_, 0, 0, 0);
    xupdate<<<(BS * D_ / 4 + 255) / 256, 256, 0, stream>>>(
        xin.h, xin.l, (const float4*)scl, (const float4*)lin, sX.h, sX.l, BS * D_ / 4);
  }

  // projections
  mgemm<0, true, false, true, true, false><<<dim3(128, 8, 1), 256, 0, stream>>>(
      nullptr, sX.h, sX.l, nullptr, sWk.h, sWk.l, bk, nullptr,
      Kp, nullptr, nullptr, BS, D_, D_, D_, 0, 0, 0);
  mgemm<0, true, false, true, true, false><<<dim3(128, 8, 1), 256, 0, stream>>>(
      nullptr, sX.h, sX.l, nullptr, sWv.h, sWv.l, bv, nullptr,
      Vp, nullptr, nullptr, BS, D_, D_, D_, 0, 0, 0);
  mgemm<0, true, false, false, true, false><<<dim3(1, 8, 1), 256, 0, stream>>>(
      aspsb, nullptr, nullptr, nullptr, sWq.h, sWq.l, bq, nullptr,
      qp, nullptr, nullptr, B_, D_, D_, D_, 0, 0, 0);

  final_sc_k<<<B_, 256, 0, stream>>>(qp, Kp, sent_mask, outsc);
  out_vec_k<<<B_, D_, 0, stream>>>(outsc, Vp, outv);
  logits_k<<<B_, 192, 0, stream>>>(outv, Wd, bd, logits);
}